// Round 1
// baseline (590.871 us; speedup 1.0000x reference)
//
#include <hip/hip_runtime.h>

#define BATCH 64
#define MM 512
#define NN 512
#define DDIM 64
#define NDIAG (MM + NN - 1)   // 1023
#define BIGV 1e10f

// ---------------------------------------------------------------------------
// Kernel 1: D[b][i][j] = sum_k (x[b][i][k] - y[b][j][k])^2
// 64x64 output tile per block, 256 threads, 4x4 register blocking, LDS staged.
// ---------------------------------------------------------------------------
__global__ __launch_bounds__(256) void compute_d_kernel(const float* __restrict__ x,
                                                        const float* __restrict__ y,
                                                        float* __restrict__ D) {
    __shared__ float xs[64][68];   // row stride 68 floats = 272 B (16B aligned)
    __shared__ float ys[64][68];
    const int b  = blockIdx.z;
    const int i0 = blockIdx.y * 64;
    const int j0 = blockIdx.x * 64;
    const int tid = threadIdx.x;

    const float* xb = x + ((size_t)b * MM + i0) * DDIM;
    const float* yb = y + ((size_t)b * NN + j0) * DDIM;

#pragma unroll
    for (int it = 0; it < 4; ++it) {
        int lin = (it * 256 + tid) * 4;   // 0..4095 step 4
        int m = lin >> 6;                 // tile row
        int k = lin & 63;                 // k offset (multiple of 4)
        float4 vx = *(const float4*)(xb + m * DDIM + k);
        float4 vy = *(const float4*)(yb + m * DDIM + k);
        xs[m][k]     = vx.x; xs[m][k + 1] = vx.y;
        xs[m][k + 2] = vx.z; xs[m][k + 3] = vx.w;
        ys[m][k]     = vy.x; ys[m][k + 1] = vy.y;
        ys[m][k + 2] = vy.z; ys[m][k + 3] = vy.w;
    }
    __syncthreads();

    const int tx = tid & 15, ty = tid >> 4;
    const int ii = ty * 4, jj = tx * 4;

    float acc[4][4];
#pragma unroll
    for (int r = 0; r < 4; ++r)
#pragma unroll
        for (int c = 0; c < 4; ++c) acc[r][c] = 0.0f;

    for (int k = 0; k < 64; k += 4) {
        float4 av[4], bv[4];
#pragma unroll
        for (int r = 0; r < 4; ++r) av[r] = *(const float4*)&xs[ii + r][k];
#pragma unroll
        for (int c = 0; c < 4; ++c) bv[c] = *(const float4*)&ys[jj + c][k];
#pragma unroll
        for (int r = 0; r < 4; ++r)
#pragma unroll
            for (int c = 0; c < 4; ++c) {
                float d0 = av[r].x - bv[c].x;
                float d1 = av[r].y - bv[c].y;
                float d2 = av[r].z - bv[c].z;
                float d3 = av[r].w - bv[c].w;
                acc[r][c] = fmaf(d0, d0, acc[r][c]);
                acc[r][c] = fmaf(d1, d1, acc[r][c]);
                acc[r][c] = fmaf(d2, d2, acc[r][c]);
                acc[r][c] = fmaf(d3, d3, acc[r][c]);
            }
    }

    float* Dp = D + ((size_t)b * MM + i0) * NN + j0;
#pragma unroll
    for (int r = 0; r < 4; ++r) {
        float4 v = make_float4(acc[r][0], acc[r][1], acc[r][2], acc[r][3]);
        *(float4*)(Dp + (size_t)(ii + r) * NN + jj) = v;
    }
}

// ---------------------------------------------------------------------------
// Kernel 2: soft-DTW DP, one block per batch. Thread t owns row i=t.
// Rolling anti-diagonal buffers in LDS (padded slot 0 = BIG boundary).
// Thread t's D accesses stream contiguously along row t -> float4 dbuf.
// ---------------------------------------------------------------------------
__global__ __launch_bounds__(512) void softdtw_kernel(const float* __restrict__ D,
                                                      float* __restrict__ out_pb) {
    __shared__ float bufA[MM + 1], bufB[MM + 1], bufC[MM + 1];
    const int b = blockIdx.x;
    const int t = threadIdx.x;           // row index i
    const float* Drow = D + ((size_t)b * MM + t) * NN;

    if (t == 0) { bufA[0] = BIGV; bufB[0] = BIGV; bufC[0] = BIGV; }

    // double-buffered row stream
    float4 cur4 = *(const float4*)(Drow);
    float4 nxt4 = *(const float4*)(Drow + 4);
    __syncthreads();

    float* cur = bufA;   // diagonal d
    float* prv = bufB;   // diagonal d-1
    float* pp  = bufC;   // diagonal d-2

    const float K2E  = 14.426950408889634f;    // log2(e)/gamma, gamma=0.1
    const float GLN2 = 0.06931471805599453f;   // gamma*ln(2)
    const float d0val = (t == 0) ? 0.0f : BIGV; // R[-1][-1]=0 only for (0,0)

    float res = 0.0f;
    int j = -t;   // j = d - t

    for (int d = 0; d < NDIAG; ++d) {
        if (j >= 0 && j < NN) {
            float dlo = (j & 1) ? cur4.y : cur4.x;
            float dhi = (j & 1) ? cur4.w : cur4.z;
            float Dv  = (j & 2) ? dhi : dlo;

            float r1 = prv[t];                        // R[i-1][j]   (slot pad)
            float r2 = (j == 0) ? BIGV : prv[t + 1];  // R[i][j-1]
            float r0 = (j == 0) ? d0val : pp[t];      // R[i-1][j-1]

            float mn = fminf(fminf(r0, r1), r2);
            float s = __builtin_amdgcn_exp2f((mn - r0) * K2E)
                    + __builtin_amdgcn_exp2f((mn - r1) * K2E)
                    + __builtin_amdgcn_exp2f((mn - r2) * K2E);
            float val = Dv + mn - GLN2 * __builtin_amdgcn_logf(s);

            cur[t + 1] = val;
            res = val;

            if ((j & 3) == 3) {          // consumed cur4: rotate + prefetch
                cur4 = nxt4;
                if (j < 504) nxt4 = *(const float4*)(Drow + j + 5);
            }
        }
        ++j;
        float* tmp = pp; pp = prv; prv = cur; cur = tmp;
        __syncthreads();
    }
    if (t == MM - 1) out_pb[b] = res;    // thread 511's last value = R[511][511]
}

// ---------------------------------------------------------------------------
// Kernel 3: mean over 64 per-batch results
// ---------------------------------------------------------------------------
__global__ void reduce_mean_kernel(const float* __restrict__ pb, float* __restrict__ out) {
    float v = pb[threadIdx.x];
#pragma unroll
    for (int off = 32; off > 0; off >>= 1) v += __shfl_down(v, off, 64);
    if (threadIdx.x == 0) out[0] = v * (1.0f / 64.0f);
}

extern "C" void kernel_launch(void* const* d_in, const int* in_sizes, int n_in,
                              void* d_out, int out_size, void* d_ws, size_t ws_size,
                              hipStream_t stream) {
    const float* x = (const float*)d_in[0];   // (64, 512, 64) fp32
    const float* y = (const float*)d_in[1];   // (64, 512, 64) fp32

    float* D  = (float*)d_ws;                               // 64*512*512 floats = 64 MB
    float* pb = D + (size_t)BATCH * MM * NN;                // 64 floats

    compute_d_kernel<<<dim3(NN / 64, MM / 64, BATCH), 256, 0, stream>>>(x, y, D);
    softdtw_kernel<<<BATCH, MM, 0, stream>>>(D, pb);
    reduce_mean_kernel<<<1, 64, 0, stream>>>(pb, (float*)d_out);
}

// Round 2
// 409.697 us; speedup vs baseline: 1.4422x; 1.4422x over previous
//
#include <hip/hip_runtime.h>

#define BATCH 64
#define MM 512
#define NN 512
#define DDIM 64

#define K2E   14.426950408889634f     // log2(e)/gamma, gamma=0.1
#define GLN2  0.06931471805599453f    // gamma*ln(2)  (= 1/K2E)
#define NEGB  (-1.4426950e11f)        // t-domain encoding of R=BIG=1e10

// ---------------------------------------------------------------------------
// Kernel 1: D'[b][i][j] = -K2E * max(0, |x_i|^2 + |y_j|^2 - 2 x_i.y_j)
// 128x128 tile per block, 256 threads, 8x8 register blocking, k-major LDS.
// ---------------------------------------------------------------------------
__global__ __launch_bounds__(256) void compute_d_kernel(const float* __restrict__ x,
                                                        const float* __restrict__ y,
                                                        float* __restrict__ D) {
    __shared__ __align__(16) float xs[64][132];   // [k][row], stride 132 (16B aligned rows)
    __shared__ __align__(16) float ys[64][132];
    __shared__ float xnk[128], ynk[128];          // K2E * row norms

    const int b  = blockIdx.z;
    const int i0 = blockIdx.y * 128;
    const int j0 = blockIdx.x * 128;
    const int tid = threadIdx.x;

    const float* xb = x + ((size_t)b * MM + i0) * DDIM;
    const float* yb = y + ((size_t)b * NN + j0) * DDIM;

    // stage 128 rows x 64 k, transposed into LDS (writes: lanes -> consecutive rows)
#pragma unroll
    for (int it = 0; it < 8; ++it) {
        int idx = it * 256 + tid;        // 0..2047 float4-slots
        int row = idx & 127;
        int k4  = idx >> 7;              // 0..15
        float4 vx = *(const float4*)(xb + row * DDIM + k4 * 4);
        float4 vy = *(const float4*)(yb + row * DDIM + k4 * 4);
        xs[k4 * 4 + 0][row] = vx.x; xs[k4 * 4 + 1][row] = vx.y;
        xs[k4 * 4 + 2][row] = vx.z; xs[k4 * 4 + 3][row] = vx.w;
        ys[k4 * 4 + 0][row] = vy.x; ys[k4 * 4 + 1][row] = vy.y;
        ys[k4 * 4 + 2][row] = vy.z; ys[k4 * 4 + 3][row] = vy.w;
    }
    __syncthreads();

    // row norms (threads 0-127: x, 128-255: y)
    {
        int r = tid & 127;
        float s = 0.0f;
        if (tid < 128) {
            for (int k = 0; k < 64; ++k) { float v = xs[k][r]; s = fmaf(v, v, s); }
            xnk[r] = K2E * s;
        } else {
            for (int k = 0; k < 64; ++k) { float v = ys[k][r]; s = fmaf(v, v, s); }
            ynk[r] = K2E * s;
        }
    }
    __syncthreads();

    const int tx = tid & 15, ty = tid >> 4;
    const int ii = ty * 8, jj = tx * 8;

    float acc[8][8];
#pragma unroll
    for (int r = 0; r < 8; ++r)
#pragma unroll
        for (int c = 0; c < 8; ++c) acc[r][c] = 0.0f;

    for (int k = 0; k < 64; ++k) {
        float4 a0 = *(const float4*)&xs[k][ii];
        float4 a1 = *(const float4*)&xs[k][ii + 4];
        float4 b0 = *(const float4*)&ys[k][jj];
        float4 b1 = *(const float4*)&ys[k][jj + 4];
        float av[8] = {a0.x, a0.y, a0.z, a0.w, a1.x, a1.y, a1.z, a1.w};
        float bv[8] = {b0.x, b0.y, b0.z, b0.w, b1.x, b1.y, b1.z, b1.w};
#pragma unroll
        for (int r = 0; r < 8; ++r)
#pragma unroll
            for (int c = 0; c < 8; ++c) acc[r][c] = fmaf(av[r], bv[c], acc[r][c]);
    }

    // epilogue: D' = min(0, 2*K2E*acc - K2E*xn - K2E*yn)
    float Ar[8], Bc[8];
#pragma unroll
    for (int r = 0; r < 8; ++r) Ar[r] = xnk[ii + r];
#pragma unroll
    for (int c = 0; c < 8; ++c) Bc[c] = ynk[jj + c];

    const float twoK = 2.0f * K2E;
    float* Dp = D + ((size_t)b * MM + i0 + ii) * NN + j0 + jj;
#pragma unroll
    for (int r = 0; r < 8; ++r) {
        float o[8];
#pragma unroll
        for (int c = 0; c < 8; ++c) {
            float v = fmaf(acc[r][c], twoK, -Ar[r]) - Bc[c];
            o[c] = fminf(v, 0.0f);
        }
        *(float4*)(Dp + (size_t)r * NN)     = make_float4(o[0], o[1], o[2], o[3]);
        *(float4*)(Dp + (size_t)r * NN + 4) = make_float4(o[4], o[5], o[6], o[7]);
    }
}

// ---------------------------------------------------------------------------
// Kernel 2: soft-DTW DP in t-domain (t = -R*K2E). One WAVE per batch.
// Lane t owns rows [8t, 8t+8); tiles are 8x4 cells, processed in registers in
// anti-diagonal order. Boundary row passes lane->lane via __shfl_up. No LDS,
// no __syncthreads. 64+128-1 = 191 macro steps.
// ---------------------------------------------------------------------------
__global__ __launch_bounds__(64) void softdtw_kernel(const float* __restrict__ D,
                                                     float* __restrict__ out_pb) {
    const int b = blockIdx.x;
    const int t = threadIdx.x;                       // lane = tile-row
    const float* Db = D + ((size_t)b * MM + (size_t)t * 8) * NN;

    float left[8], top[4], bot[4];
#pragma unroll
    for (int r = 0; r < 8; ++r) left[r] = NEGB;
#pragma unroll
    for (int k = 0; k < 4; ++k) { top[k] = NEGB; bot[k] = NEGB; }
    float tl = (t == 0) ? 0.0f : NEGB;               // t-domain R[-1][-1]=0

    float4 dcur[8], dn[8];
#pragma unroll
    for (int r = 0; r < 8; ++r) dcur[r] = *(const float4*)(Db + r * NN);

    for (int s = 0; s < 191; ++s) {
        const int c = s - t;
        const bool active = (c >= 0) & (c < 128);
        if (active) {
            if (c < 127) {
#pragma unroll
                for (int r = 0; r < 8; ++r)
                    dn[r] = *(const float4*)(Db + r * NN + 4 * (c + 1));
            }
            float Rt[8][4];
#pragma unroll
            for (int dd = 0; dd <= 10; ++dd) {
#pragma unroll
                for (int r = 0; r < 8; ++r) {
                    const int cl = dd - r;
                    if (cl < 0 || cl > 3) continue;
                    float dg, up, lf;
                    if (r == 0) { dg = (cl == 0) ? tl : top[cl - 1]; up = top[cl]; }
                    else        { dg = (cl == 0) ? left[r - 1] : Rt[r - 1][cl - 1]; up = Rt[r - 1][cl]; }
                    lf = (cl == 0) ? left[r] : Rt[r][cl - 1];
                    float Dv = (cl == 0) ? dcur[r].x : (cl == 1) ? dcur[r].y
                             : (cl == 2) ? dcur[r].z : dcur[r].w;
                    float mx = fmaxf(fmaxf(dg, up), lf);
                    float mn = fminf(fminf(dg, up), lf);
                    float md = __builtin_amdgcn_fmed3f(dg, up, lf);
                    float e1 = __builtin_amdgcn_exp2f(md - mx);
                    float e2 = __builtin_amdgcn_exp2f(mn - mx);
                    float lg = __builtin_amdgcn_logf(1.0f + e1 + e2);
                    Rt[r][cl] = mx + lg + Dv;
                }
            }
#pragma unroll
            for (int r = 0; r < 8; ++r) left[r] = Rt[r][3];
#pragma unroll
            for (int k = 0; k < 4; ++k) bot[k] = Rt[7][k];
            if (c < 127) {
#pragma unroll
                for (int r = 0; r < 8; ++r) dcur[r] = dn[r];
            }
        }
        // exchange (all 64 lanes, uniform — shuffles outside divergent branch)
        float ntl = top[3];
#pragma unroll
        for (int k = 0; k < 4; ++k) {
            float v = __shfl_up(bot[k], 1, 64);
            top[k] = (t == 0) ? NEGB : v;
        }
        tl = (t == 0) ? NEGB : ntl;
    }
    if (t == 63) out_pb[b] = bot[3];   // t-value of R[511][511]
}

// ---------------------------------------------------------------------------
// Kernel 3: mean over 64 per-batch t-values, convert back: R = -GLN2 * t
// ---------------------------------------------------------------------------
__global__ void reduce_mean_kernel(const float* __restrict__ pb, float* __restrict__ out) {
    float v = pb[threadIdx.x];
#pragma unroll
    for (int off = 32; off > 0; off >>= 1) v += __shfl_down(v, off, 64);
    if (threadIdx.x == 0) out[0] = v * (-GLN2 / 64.0f);
}

extern "C" void kernel_launch(void* const* d_in, const int* in_sizes, int n_in,
                              void* d_out, int out_size, void* d_ws, size_t ws_size,
                              hipStream_t stream) {
    const float* x = (const float*)d_in[0];   // (64, 512, 64) fp32
    const float* y = (const float*)d_in[1];   // (64, 512, 64) fp32

    float* D  = (float*)d_ws;                               // 64 MB (t-domain scaled)
    float* pb = D + (size_t)BATCH * MM * NN;                // 64 floats

    compute_d_kernel<<<dim3(NN / 128, MM / 128, BATCH), 256, 0, stream>>>(x, y, D);
    softdtw_kernel<<<BATCH, 64, 0, stream>>>(D, pb);
    reduce_mean_kernel<<<1, 64, 0, stream>>>(pb, (float*)d_out);
}

// Round 3
// 376.776 us; speedup vs baseline: 1.5682x; 1.0874x over previous
//
#include <hip/hip_runtime.h>

#define BATCH 64
#define MM 512
#define NN 512
#define DDIM 64

#define K2E   14.426950408889634f     // log2(e)/gamma, gamma=0.1
#define GLN2  0.06931471805599453f    // gamma*ln(2)
#define NEGB  (-1.4426950e11f)        // t-domain encoding of R=BIG=1e10

// ---------------------------------------------------------------------------
// Kernel 1: t-domain distances D' = -K2E * max(0, |x_i - y_j|^2), stored
// BLOCK-LINEAR in DP tile order: P[b][t][m'][r][c], t=i>>3, m'=j>>2, r=i&7,
// c=j&3. Each DP lane-step then reads one contiguous 128 B chunk.
// 128x128 tile per block, 256 threads, 8x8 register blocking, k-major LDS.
// ---------------------------------------------------------------------------
__global__ __launch_bounds__(256) void compute_d_kernel(const float* __restrict__ x,
                                                        const float* __restrict__ y,
                                                        float* __restrict__ P) {
    __shared__ __align__(16) float xs[64][132];   // [k][row]
    __shared__ __align__(16) float ys[64][132];
    __shared__ float xnk[128], ynk[128];          // K2E * row norms

    const int b  = blockIdx.z;
    const int i0 = blockIdx.y * 128;
    const int j0 = blockIdx.x * 128;
    const int tid = threadIdx.x;

    const float* xb = x + ((size_t)b * MM + i0) * DDIM;
    const float* yb = y + ((size_t)b * NN + j0) * DDIM;

#pragma unroll
    for (int it = 0; it < 8; ++it) {
        int idx = it * 256 + tid;        // 0..2047 float4-slots
        int row = idx & 127;
        int k4  = idx >> 7;              // 0..15
        float4 vx = *(const float4*)(xb + row * DDIM + k4 * 4);
        float4 vy = *(const float4*)(yb + row * DDIM + k4 * 4);
        xs[k4 * 4 + 0][row] = vx.x; xs[k4 * 4 + 1][row] = vx.y;
        xs[k4 * 4 + 2][row] = vx.z; xs[k4 * 4 + 3][row] = vx.w;
        ys[k4 * 4 + 0][row] = vy.x; ys[k4 * 4 + 1][row] = vy.y;
        ys[k4 * 4 + 2][row] = vy.z; ys[k4 * 4 + 3][row] = vy.w;
    }
    __syncthreads();

    {
        int r = tid & 127;
        float s = 0.0f;
        if (tid < 128) {
            for (int k = 0; k < 64; ++k) { float v = xs[k][r]; s = fmaf(v, v, s); }
            xnk[r] = K2E * s;
        } else {
            for (int k = 0; k < 64; ++k) { float v = ys[k][r]; s = fmaf(v, v, s); }
            ynk[r] = K2E * s;
        }
    }
    __syncthreads();

    const int tx = tid & 15, ty = tid >> 4;
    const int ii = ty * 8, jj = tx * 8;

    float acc[8][8];
#pragma unroll
    for (int r = 0; r < 8; ++r)
#pragma unroll
        for (int c = 0; c < 8; ++c) acc[r][c] = 0.0f;

    for (int k = 0; k < 64; ++k) {
        float4 a0 = *(const float4*)&xs[k][ii];
        float4 a1 = *(const float4*)&xs[k][ii + 4];
        float4 b0 = *(const float4*)&ys[k][jj];
        float4 b1 = *(const float4*)&ys[k][jj + 4];
        float av[8] = {a0.x, a0.y, a0.z, a0.w, a1.x, a1.y, a1.z, a1.w};
        float bv[8] = {b0.x, b0.y, b0.z, b0.w, b1.x, b1.y, b1.z, b1.w};
#pragma unroll
        for (int r = 0; r < 8; ++r)
#pragma unroll
            for (int c = 0; c < 8; ++c) acc[r][c] = fmaf(av[r], bv[c], acc[r][c]);
    }

    float Ar[8], Bc[8];
#pragma unroll
    for (int r = 0; r < 8; ++r) Ar[r] = xnk[ii + r];
#pragma unroll
    for (int c = 0; c < 8; ++c) Bc[c] = ynk[jj + c];

    const float twoK = 2.0f * K2E;
    // block-linear destination: this thread owns exactly blocks (tg, mg) and (tg, mg+1)
    const int tg = (i0 >> 3) + ty;        // 0..63
    const int mg = (j0 >> 2) + tx * 2;    // 0..126 (even)
    float* Pp = P + (size_t)b * (MM * NN) + ((size_t)tg * 128 + mg) * 32;
#pragma unroll
    for (int r = 0; r < 8; ++r) {
        float o[8];
#pragma unroll
        for (int c = 0; c < 8; ++c) {
            float v = fmaf(acc[r][c], twoK, -Ar[r]) - Bc[c];
            o[c] = fminf(v, 0.0f);
        }
        *(float4*)(Pp + r * 4)      = make_float4(o[0], o[1], o[2], o[3]);
        *(float4*)(Pp + 32 + r * 4) = make_float4(o[4], o[5], o[6], o[7]);
    }
}

// ---------------------------------------------------------------------------
// Kernel 2: soft-DTW DP in t-domain. One wave per batch, lane t owns rows
// [8t,8t+8), 8x4 cell tiles, 191 macro steps, shuffle-passed boundaries.
// Block-linear P: lane reads contiguous 128 B per step; explicit unroll-by-2
// ping-pong (da/db) register prefetch keeps the next chunk in flight.
// ---------------------------------------------------------------------------
__global__ __launch_bounds__(64) void softdtw_kernel(const float* __restrict__ P,
                                                     float* __restrict__ out) {
    const int b = blockIdx.x;
    const int t = threadIdx.x;
    const float* Pb = P + (size_t)b * (MM * NN) + (size_t)t * 4096;  // t*128*32

    float4 da[8], db[8];
#pragma unroll
    for (int r = 0; r < 8; ++r) da[r] = *(const float4*)(Pb + r * 4);  // c=0

    float left[8], top[4], bot[4];
#pragma unroll
    for (int r = 0; r < 8; ++r) left[r] = NEGB;
#pragma unroll
    for (int k = 0; k < 4; ++k) { top[k] = NEGB; bot[k] = NEGB; }
    float tl = (t == 0) ? 0.0f : NEGB;

#define DTW_STEP(S, CUR, NXT)                                                   \
    {                                                                           \
        const int c  = (S) - t;                                                 \
        const int cn = c + 1;                                                   \
        if (cn >= 0 && cn < 128) {                                              \
            _Pragma("unroll")                                                   \
            for (int r = 0; r < 8; ++r)                                         \
                NXT[r] = *(const float4*)(Pb + cn * 32 + r * 4);                \
        }                                                                       \
        if (c >= 0 && c < 128) {                                                \
            float Rt[8][4];                                                     \
            _Pragma("unroll")                                                   \
            for (int dd = 0; dd <= 10; ++dd) {                                  \
                _Pragma("unroll")                                               \
                for (int r = 0; r < 8; ++r) {                                   \
                    const int cl = dd - r;                                      \
                    if (cl < 0 || cl > 3) continue;                             \
                    float dg, up, lf;                                           \
                    if (r == 0) { dg = (cl == 0) ? tl : top[cl - 1]; up = top[cl]; } \
                    else        { dg = (cl == 0) ? left[r - 1] : Rt[r - 1][cl - 1]; up = Rt[r - 1][cl]; } \
                    lf = (cl == 0) ? left[r] : Rt[r][cl - 1];                   \
                    float Dv = (cl == 0) ? CUR[r].x : (cl == 1) ? CUR[r].y      \
                             : (cl == 2) ? CUR[r].z : CUR[r].w;                 \
                    float mx = fmaxf(fmaxf(dg, up), lf);                        \
                    float mn = fminf(fminf(dg, up), lf);                        \
                    float md = __builtin_amdgcn_fmed3f(dg, up, lf);             \
                    float e1 = __builtin_amdgcn_exp2f(md - mx);                 \
                    float e2 = __builtin_amdgcn_exp2f(mn - mx);                 \
                    float lg = __builtin_amdgcn_logf(1.0f + e1 + e2);           \
                    Rt[r][cl] = mx + lg + Dv;                                   \
                }                                                               \
            }                                                                   \
            _Pragma("unroll")                                                   \
            for (int r = 0; r < 8; ++r) left[r] = Rt[r][3];                     \
            _Pragma("unroll")                                                   \
            for (int k = 0; k < 4; ++k) bot[k] = Rt[7][k];                      \
        }                                                                       \
        float ntl = top[3];                                                     \
        _Pragma("unroll")                                                       \
        for (int k = 0; k < 4; ++k) {                                           \
            float v = __shfl_up(bot[k], 1, 64);                                 \
            top[k] = (t == 0) ? NEGB : v;                                       \
        }                                                                       \
        tl = (t == 0) ? NEGB : ntl;                                             \
    }

    for (int p = 0; p < 95; ++p) {
        DTW_STEP(2 * p,     da, db)
        DTW_STEP(2 * p + 1, db, da)
    }
    DTW_STEP(190, da, db)
#undef DTW_STEP

    if (t == 63) atomicAdd(out, bot[3] * (-GLN2 / 64.0f));
}

extern "C" void kernel_launch(void* const* d_in, const int* in_sizes, int n_in,
                              void* d_out, int out_size, void* d_ws, size_t ws_size,
                              hipStream_t stream) {
    const float* x = (const float*)d_in[0];   // (64, 512, 64) fp32
    const float* y = (const float*)d_in[1];   // (64, 512, 64) fp32

    float* P = (float*)d_ws;                  // 64 MB, block-linear t-domain D

    hipMemsetAsync(d_out, 0, sizeof(float), stream);
    compute_d_kernel<<<dim3(NN / 128, MM / 128, BATCH), 256, 0, stream>>>(x, y, P);
    softdtw_kernel<<<BATCH, 64, 0, stream>>>(P, (float*)d_out);
}

// Round 5
// 320.075 us; speedup vs baseline: 1.8460x; 1.1771x over previous
//
#include <hip/hip_runtime.h>

#define BATCH 64
#define MM 512
#define NN 512
#define DDIM 64

#define K2E   14.426950408889634f     // log2(e)/gamma, gamma=0.1
#define GLN2  0.06931471805599453f    // gamma*ln(2)
#define NEGB  (-1.4426950e11f)        // t-domain encoding of R=BIG=1e10

// ---------------------------------------------------------------------------
// Kernel 1: t-domain distances D' = -K2E * max(0, |x_i - y_j|^2), stored
// BLOCK-LINEAR in DP tile order: P[b][t][m'][r][c], t=i>>3, m'=j>>2, r=i&7,
// c=j&3. Each DP lane-step reads one contiguous 128 B chunk.
// ---------------------------------------------------------------------------
__global__ __launch_bounds__(256) void compute_d_kernel(const float* __restrict__ x,
                                                        const float* __restrict__ y,
                                                        float* __restrict__ P) {
    __shared__ __align__(16) float xs[64][132];   // [k][row]
    __shared__ __align__(16) float ys[64][132];
    __shared__ float xnk[128], ynk[128];          // K2E * row norms

    const int b  = blockIdx.z;
    const int i0 = blockIdx.y * 128;
    const int j0 = blockIdx.x * 128;
    const int tid = threadIdx.x;

    const float* xb = x + ((size_t)b * MM + i0) * DDIM;
    const float* yb = y + ((size_t)b * NN + j0) * DDIM;

#pragma unroll
    for (int it = 0; it < 8; ++it) {
        int idx = it * 256 + tid;        // 0..2047 float4-slots
        int row = idx & 127;
        int k4  = idx >> 7;              // 0..15
        float4 vx = *(const float4*)(xb + row * DDIM + k4 * 4);
        float4 vy = *(const float4*)(yb + row * DDIM + k4 * 4);
        xs[k4 * 4 + 0][row] = vx.x; xs[k4 * 4 + 1][row] = vx.y;
        xs[k4 * 4 + 2][row] = vx.z; xs[k4 * 4 + 3][row] = vx.w;
        ys[k4 * 4 + 0][row] = vy.x; ys[k4 * 4 + 1][row] = vy.y;
        ys[k4 * 4 + 2][row] = vy.z; ys[k4 * 4 + 3][row] = vy.w;
    }
    __syncthreads();

    {
        int r = tid & 127;
        float s = 0.0f;
        if (tid < 128) {
            for (int k = 0; k < 64; ++k) { float v = xs[k][r]; s = fmaf(v, v, s); }
            xnk[r] = K2E * s;
        } else {
            for (int k = 0; k < 64; ++k) { float v = ys[k][r]; s = fmaf(v, v, s); }
            ynk[r] = K2E * s;
        }
    }
    __syncthreads();

    const int tx = tid & 15, ty = tid >> 4;
    const int ii = ty * 8, jj = tx * 8;

    float acc[8][8];
#pragma unroll
    for (int r = 0; r < 8; ++r)
#pragma unroll
        for (int c = 0; c < 8; ++c) acc[r][c] = 0.0f;

    for (int k = 0; k < 64; ++k) {
        float4 a0 = *(const float4*)&xs[k][ii];
        float4 a1 = *(const float4*)&xs[k][ii + 4];
        float4 b0 = *(const float4*)&ys[k][jj];
        float4 b1 = *(const float4*)&ys[k][jj + 4];
        float av[8] = {a0.x, a0.y, a0.z, a0.w, a1.x, a1.y, a1.z, a1.w};
        float bv[8] = {b0.x, b0.y, b0.z, b0.w, b1.x, b1.y, b1.z, b1.w};
#pragma unroll
        for (int r = 0; r < 8; ++r)
#pragma unroll
            for (int c = 0; c < 8; ++c) acc[r][c] = fmaf(av[r], bv[c], acc[r][c]);
    }

    float Ar[8], Bc[8];
#pragma unroll
    for (int r = 0; r < 8; ++r) Ar[r] = xnk[ii + r];
#pragma unroll
    for (int c = 0; c < 8; ++c) Bc[c] = ynk[jj + c];

    const float twoK = 2.0f * K2E;
    const int tg = (i0 >> 3) + ty;        // 0..63
    const int mg = (j0 >> 2) + tx * 2;    // 0..126 (even)
    float* Pp = P + (size_t)b * (MM * NN) + ((size_t)tg * 128 + mg) * 32;
#pragma unroll
    for (int r = 0; r < 8; ++r) {
        float o[8];
#pragma unroll
        for (int c = 0; c < 8; ++c) {
            float v = fmaf(acc[r][c], twoK, -Ar[r]) - Bc[c];
            o[c] = fminf(v, 0.0f);
        }
        *(float4*)(Pp + r * 4)      = make_float4(o[0], o[1], o[2], o[3]);
        *(float4*)(Pp + 32 + r * 4) = make_float4(o[4], o[5], o[6], o[7]);
    }
}

// ---------------------------------------------------------------------------
// Kernel 2: soft-DTW DP, t-domain, one wave per batch, lane t owns rows
// [8t,8t+8), 8x4 tiles, 191 steps. Triple-buffered register prefetch
// (distance 2) FORCED via inline-asm global_load_dwordx4 + manual
// s_waitcnt vmcnt(8) tying the consumed buffer as 32 SCALAR "+v" operands
// (float4 tuple ties are unsupported: "tied indirect register inputs").
// ---------------------------------------------------------------------------
__global__ __launch_bounds__(64, 1) void softdtw_kernel(const float* __restrict__ P,
                                                        float* __restrict__ out) {
    const int b = blockIdx.x;
    const int t = threadIdx.x;
    const float* Pb = P + (size_t)b * (MM * NN) + (size_t)t * 4096;  // t*128*32

    float4 b0[8], b1[8], b2[8];

    // issue 8 prefetch loads for chunk clamp(CN) into BUF
#define LOADS(BUF, CN)                                                          \
    {                                                                           \
        int cc = (CN); cc = cc < 0 ? 0 : (cc > 127 ? 127 : cc);                 \
        const float* ap = Pb + cc * 32;                                         \
        asm volatile("global_load_dwordx4 %0, %1, off"            : "=v"(BUF[0]) : "v"(ap)); \
        asm volatile("global_load_dwordx4 %0, %1, off offset:16"  : "=v"(BUF[1]) : "v"(ap)); \
        asm volatile("global_load_dwordx4 %0, %1, off offset:32"  : "=v"(BUF[2]) : "v"(ap)); \
        asm volatile("global_load_dwordx4 %0, %1, off offset:48"  : "=v"(BUF[3]) : "v"(ap)); \
        asm volatile("global_load_dwordx4 %0, %1, off offset:64"  : "=v"(BUF[4]) : "v"(ap)); \
        asm volatile("global_load_dwordx4 %0, %1, off offset:80"  : "=v"(BUF[5]) : "v"(ap)); \
        asm volatile("global_load_dwordx4 %0, %1, off offset:96"  : "=v"(BUF[6]) : "v"(ap)); \
        asm volatile("global_load_dwordx4 %0, %1, off offset:112" : "=v"(BUF[7]) : "v"(ap)); \
    }

    // wait until the oldest 8 loads (CUR's) have landed; tie every CUR scalar
    // so all uses are ordered after the wait
#define WAITCUR(CUR)                                                            \
    asm volatile("s_waitcnt vmcnt(8)"                                           \
                 : "+v"(CUR[0].x), "+v"(CUR[0].y), "+v"(CUR[0].z), "+v"(CUR[0].w), \
                   "+v"(CUR[1].x), "+v"(CUR[1].y), "+v"(CUR[1].z), "+v"(CUR[1].w), \
                   "+v"(CUR[2].x), "+v"(CUR[2].y), "+v"(CUR[2].z), "+v"(CUR[2].w), \
                   "+v"(CUR[3].x), "+v"(CUR[3].y), "+v"(CUR[3].z), "+v"(CUR[3].w), \
                   "+v"(CUR[4].x), "+v"(CUR[4].y), "+v"(CUR[4].z), "+v"(CUR[4].w), \
                   "+v"(CUR[5].x), "+v"(CUR[5].y), "+v"(CUR[5].z), "+v"(CUR[5].w), \
                   "+v"(CUR[6].x), "+v"(CUR[6].y), "+v"(CUR[6].z), "+v"(CUR[6].w), \
                   "+v"(CUR[7].x), "+v"(CUR[7].y), "+v"(CUR[7].z), "+v"(CUR[7].w));

    LOADS(b0, 0 - t)       // chunk for step 0
    LOADS(b1, 1 - t)       // chunk for step 1

    float left[8], top[4], bot[4];
#pragma unroll
    for (int r = 0; r < 8; ++r) left[r] = NEGB;
#pragma unroll
    for (int k = 0; k < 4; ++k) { top[k] = NEGB; bot[k] = NEGB; }
    float tl = (t == 0) ? 0.0f : NEGB;

#define DTW_STEP(S, CUR, FUT)                                                   \
    {                                                                           \
        WAITCUR(CUR)                                                            \
        LOADS(FUT, (S) + 2 - t)                                                 \
        const int c = (S) - t;                                                  \
        if (c >= 0 && c < 128) {                                                \
            float Rt[8][4];                                                     \
            _Pragma("unroll")                                                   \
            for (int dd = 0; dd <= 10; ++dd) {                                  \
                _Pragma("unroll")                                               \
                for (int r = 0; r < 8; ++r) {                                   \
                    const int cl = dd - r;                                      \
                    if (cl < 0 || cl > 3) continue;                             \
                    float dg, up, lf;                                           \
                    if (r == 0) { dg = (cl == 0) ? tl : top[cl - 1]; up = top[cl]; } \
                    else        { dg = (cl == 0) ? left[r - 1] : Rt[r - 1][cl - 1]; up = Rt[r - 1][cl]; } \
                    lf = (cl == 0) ? left[r] : Rt[r][cl - 1];                   \
                    float Dv = (cl == 0) ? CUR[r].x : (cl == 1) ? CUR[r].y      \
                             : (cl == 2) ? CUR[r].z : CUR[r].w;                 \
                    float mx = fmaxf(fmaxf(dg, up), lf);                        \
                    float mn = fminf(fminf(dg, up), lf);                        \
                    float md = __builtin_amdgcn_fmed3f(dg, up, lf);             \
                    float e1 = __builtin_amdgcn_exp2f(md - mx);                 \
                    float e2 = __builtin_amdgcn_exp2f(mn - mx);                 \
                    float lg = __builtin_amdgcn_logf(1.0f + e1 + e2);           \
                    Rt[r][cl] = mx + lg + Dv;                                   \
                }                                                               \
            }                                                                   \
            _Pragma("unroll")                                                   \
            for (int r = 0; r < 8; ++r) left[r] = Rt[r][3];                     \
            _Pragma("unroll")                                                   \
            for (int k = 0; k < 4; ++k) bot[k] = Rt[7][k];                      \
        }                                                                       \
        float ntl = top[3];                                                     \
        _Pragma("unroll")                                                       \
        for (int k = 0; k < 4; ++k) {                                           \
            float v = __shfl_up(bot[k], 1, 64);                                 \
            top[k] = (t == 0) ? NEGB : v;                                       \
        }                                                                       \
        tl = (t == 0) ? NEGB : ntl;                                             \
    }

    // step s: CUR = buf[s%3], FUT = buf[(s+2)%3]
    for (int p = 0; p < 63; ++p) {
        const int s = 3 * p;
        DTW_STEP(s,     b0, b2)
        DTW_STEP(s + 1, b1, b0)
        DTW_STEP(s + 2, b2, b1)
    }
    DTW_STEP(189, b0, b2)
    DTW_STEP(190, b1, b0)
#undef DTW_STEP
#undef LOADS
#undef WAITCUR

    if (t == 63) atomicAdd(out, bot[3] * (-GLN2 / 64.0f));
}

extern "C" void kernel_launch(void* const* d_in, const int* in_sizes, int n_in,
                              void* d_out, int out_size, void* d_ws, size_t ws_size,
                              hipStream_t stream) {
    const float* x = (const float*)d_in[0];   // (64, 512, 64) fp32
    const float* y = (const float*)d_in[1];   // (64, 512, 64) fp32

    float* P = (float*)d_ws;                  // 64 MB, block-linear t-domain D

    hipMemsetAsync(d_out, 0, sizeof(float), stream);
    compute_d_kernel<<<dim3(NN / 128, MM / 128, BATCH), 256, 0, stream>>>(x, y, P);
    softdtw_kernel<<<BATCH, 64, 0, stream>>>(P, (float*)d_out);
}

// Round 8
// 305.144 us; speedup vs baseline: 1.9364x; 1.0489x over previous
//
#include <hip/hip_runtime.h>

#define BATCH 64
#define MM 512
#define NN 512
#define DDIM 64

#define K2E   14.426950408889634f     // log2(e)/gamma, gamma=0.1
#define GLN2  0.06931471805599453f    // gamma*ln(2)
#define NEGB  (-1.4426950e11f)        // t-domain encoding of R=BIG=1e10

typedef __attribute__((ext_vector_type(8))) short short8;    // 8 bf16 (4 VGPR)
typedef __attribute__((ext_vector_type(4))) float floatx4;   // MFMA acc

__device__ __forceinline__ unsigned short f2bf(float f) {
    unsigned int u = __float_as_uint(f);
    unsigned int r = (u + 0x7FFFu + ((u >> 16) & 1u)) >> 16;   // RNE
    return (unsigned short)r;
}
__device__ __forceinline__ float bf2f(unsigned short h) {
    return __uint_as_float(((unsigned int)h) << 16);
}

// ---------------------------------------------------------------------------
// Kernel 1 (MFMA): t-domain D' = min(0, 2*K2E*G - K2E|x|^2 - K2E|y|^2) where
// G = x.y via bf16 hi/lo split (hi*hi + hi*lo + lo*hi), stored block-linear
// P[b][tg][m][r][c], tg=i>>3, m=j>>2, r=i&7, c=j&3 (matches DP kernel).
// 128x128 tile / block, 256 thr = 4 waves, each wave: 2 tile-rows x 8 tile-
// cols of 16x16x32 MFMA (6 MFMAs/tile: 3 products x 2 k-halves).
// ---------------------------------------------------------------------------
#define LDSTRU 36   // uints per LDS row (72 bf16 = 64 + 8 pad; 144 B, 16B-aligned)
__global__ __launch_bounds__(256) void compute_d_kernel(const float* __restrict__ x,
                                                        const float* __restrict__ y,
                                                        float* __restrict__ P) {
    __shared__ unsigned int xhiW[128 * LDSTRU], xloW[128 * LDSTRU];
    __shared__ unsigned int yhiW[128 * LDSTRU], yloW[128 * LDSTRU];
    __shared__ float xnk[128], ynk[128];

    const int b  = blockIdx.z;
    const int i0 = blockIdx.y * 128;
    const int j0 = blockIdx.x * 128;
    const int tid = threadIdx.x;

    const float* xb = x + ((size_t)b * MM + i0) * DDIM;
    const float* yb = y + ((size_t)b * NN + j0) * DDIM;

    // ---- stage + convert to hi/lo bf16 (packed 2/uint) ----
#pragma unroll
    for (int it = 0; it < 8; ++it) {
        int idx = it * 256 + tid;        // 0..2047 float4-chunks
        int row = idx & 127;
        int k4  = idx >> 7;              // 0..15
        float4 vx = *(const float4*)(xb + row * DDIM + k4 * 4);
        float4 vy = *(const float4*)(yb + row * DDIM + k4 * 4);
        int base = row * LDSTRU + k4 * 2;

        unsigned short h0 = f2bf(vx.x), h1 = f2bf(vx.y), h2 = f2bf(vx.z), h3 = f2bf(vx.w);
        xhiW[base]     = (unsigned)h0 | ((unsigned)h1 << 16);
        xhiW[base + 1] = (unsigned)h2 | ((unsigned)h3 << 16);
        unsigned short l0 = f2bf(vx.x - bf2f(h0)), l1 = f2bf(vx.y - bf2f(h1));
        unsigned short l2 = f2bf(vx.z - bf2f(h2)), l3 = f2bf(vx.w - bf2f(h3));
        xloW[base]     = (unsigned)l0 | ((unsigned)l1 << 16);
        xloW[base + 1] = (unsigned)l2 | ((unsigned)l3 << 16);

        h0 = f2bf(vy.x); h1 = f2bf(vy.y); h2 = f2bf(vy.z); h3 = f2bf(vy.w);
        yhiW[base]     = (unsigned)h0 | ((unsigned)h1 << 16);
        yhiW[base + 1] = (unsigned)h2 | ((unsigned)h3 << 16);
        l0 = f2bf(vy.x - bf2f(h0)); l1 = f2bf(vy.y - bf2f(h1));
        l2 = f2bf(vy.z - bf2f(h2)); l3 = f2bf(vy.w - bf2f(h3));
        yloW[base]     = (unsigned)l0 | ((unsigned)l1 << 16);
        yloW[base + 1] = (unsigned)l2 | ((unsigned)l3 << 16);
    }
    __syncthreads();

    // ---- norms from RECONSTRUCTED hi+lo (consistent with MFMA Gram) ----
    {
        int r = tid & 127;
        const unsigned int* ph = (tid < 128 ? xhiW : yhiW) + r * LDSTRU;
        const unsigned int* pl = (tid < 128 ? xloW : yloW) + r * LDSTRU;
        float s = 0.0f;
#pragma unroll
        for (int kk = 0; kk < 32; ++kk) {
            unsigned int uh = ph[kk], ul = pl[kk];
            float e0 = __uint_as_float(uh << 16) + __uint_as_float(ul << 16);
            float e1 = __uint_as_float(uh & 0xFFFF0000u) + __uint_as_float(ul & 0xFFFF0000u);
            s = fmaf(e0, e0, s);
            s = fmaf(e1, e1, s);
        }
        if (tid < 128) xnk[r] = K2E * s; else ynk[r] = K2E * s;
    }
    __syncthreads();

    // ---- MFMA: wave w -> tile-rows {2w,2w+1} x tile-cols 0..7 ----
    const int wid = tid >> 6, lane = tid & 63;
    const int ln = lane & 15, q = lane >> 4;
    const unsigned short* XH = (const unsigned short*)xhiW;
    const unsigned short* XL = (const unsigned short*)xloW;
    const unsigned short* YH = (const unsigned short*)yhiW;
    const unsigned short* YL = (const unsigned short*)yloW;

#pragma unroll
    for (int tr2 = 0; tr2 < 2; ++tr2) {
        const int I0 = (wid * 2 + tr2) * 16;
        const int arow = (I0 + ln) * (2 * LDSTRU);   // ushort index of row
        short8 ah0 = *(const short8*)&XH[arow + q * 8];
        short8 ah1 = *(const short8*)&XH[arow + 32 + q * 8];
        short8 al0 = *(const short8*)&XL[arow + q * 8];
        short8 al1 = *(const short8*)&XL[arow + 32 + q * 8];

        float xnr[4];
#pragma unroll
        for (int reg = 0; reg < 4; ++reg) xnr[reg] = xnk[I0 + q * 4 + reg];

        const int Ibase = i0 + I0 + q * 4;
        float* Prow = P + (size_t)b * (MM * NN) + (size_t)(Ibase >> 3) * 4096 + (Ibase & 7) * 4;

#pragma unroll
        for (int tc = 0; tc < 8; ++tc) {
            const int J0 = tc * 16;
            const int brow = (J0 + ln) * (2 * LDSTRU);
            short8 bh0 = *(const short8*)&YH[brow + q * 8];
            short8 bh1 = *(const short8*)&YH[brow + 32 + q * 8];
            short8 bl0 = *(const short8*)&YL[brow + q * 8];
            short8 bl1 = *(const short8*)&YL[brow + 32 + q * 8];

            floatx4 acc = {0.0f, 0.0f, 0.0f, 0.0f};
            acc = __builtin_amdgcn_mfma_f32_16x16x32_bf16(ah0, bh0, acc, 0, 0, 0);
            acc = __builtin_amdgcn_mfma_f32_16x16x32_bf16(ah1, bh1, acc, 0, 0, 0);
            acc = __builtin_amdgcn_mfma_f32_16x16x32_bf16(ah0, bl0, acc, 0, 0, 0);
            acc = __builtin_amdgcn_mfma_f32_16x16x32_bf16(ah1, bl1, acc, 0, 0, 0);
            acc = __builtin_amdgcn_mfma_f32_16x16x32_bf16(al0, bh0, acc, 0, 0, 0);
            acc = __builtin_amdgcn_mfma_f32_16x16x32_bf16(al1, bh1, acc, 0, 0, 0);

            const float yn = ynk[J0 + ln];
            const int Jg = j0 + J0 + ln;
            float* Pp = Prow + (size_t)(Jg >> 2) * 32 + (Jg & 3);
#pragma unroll
            for (int reg = 0; reg < 4; ++reg) {
                float v = fmaf(acc[reg], 2.0f * K2E, -xnr[reg]) - yn;
                Pp[reg * 4] = fminf(v, 0.0f);
            }
        }
    }
}

// ---------------------------------------------------------------------------
// Kernel 2: soft-DTW DP (R5, known-good): one wave/batch, lane t owns rows
// [8t,8t+8), 8x4 tiles, 191 steps, triple-buffered asm prefetch, vmcnt(8)
// wait with scalarized register ties.
// ---------------------------------------------------------------------------
__global__ __launch_bounds__(64, 1) void softdtw_kernel(const float* __restrict__ P,
                                                        float* __restrict__ out) {
    const int b = blockIdx.x;
    const int t = threadIdx.x;
    const float* Pb = P + (size_t)b * (MM * NN) + (size_t)t * 4096;  // t*128*32

    float4 b0[8], b1[8], b2[8];

#define LOADS(BUF, CN)                                                          \
    {                                                                           \
        int cc = (CN); cc = cc < 0 ? 0 : (cc > 127 ? 127 : cc);                 \
        const float* ap = Pb + cc * 32;                                         \
        asm volatile("global_load_dwordx4 %0, %1, off"            : "=v"(BUF[0]) : "v"(ap)); \
        asm volatile("global_load_dwordx4 %0, %1, off offset:16"  : "=v"(BUF[1]) : "v"(ap)); \
        asm volatile("global_load_dwordx4 %0, %1, off offset:32"  : "=v"(BUF[2]) : "v"(ap)); \
        asm volatile("global_load_dwordx4 %0, %1, off offset:48"  : "=v"(BUF[3]) : "v"(ap)); \
        asm volatile("global_load_dwordx4 %0, %1, off offset:64"  : "=v"(BUF[4]) : "v"(ap)); \
        asm volatile("global_load_dwordx4 %0, %1, off offset:80"  : "=v"(BUF[5]) : "v"(ap)); \
        asm volatile("global_load_dwordx4 %0, %1, off offset:96"  : "=v"(BUF[6]) : "v"(ap)); \
        asm volatile("global_load_dwordx4 %0, %1, off offset:112" : "=v"(BUF[7]) : "v"(ap)); \
    }

#define WAITCUR(CUR)                                                            \
    asm volatile("s_waitcnt vmcnt(8)"                                           \
                 : "+v"(CUR[0].x), "+v"(CUR[0].y), "+v"(CUR[0].z), "+v"(CUR[0].w), \
                   "+v"(CUR[1].x), "+v"(CUR[1].y), "+v"(CUR[1].z), "+v"(CUR[1].w), \
                   "+v"(CUR[2].x), "+v"(CUR[2].y), "+v"(CUR[2].z), "+v"(CUR[2].w), \
                   "+v"(CUR[3].x), "+v"(CUR[3].y), "+v"(CUR[3].z), "+v"(CUR[3].w), \
                   "+v"(CUR[4].x), "+v"(CUR[4].y), "+v"(CUR[4].z), "+v"(CUR[4].w), \
                   "+v"(CUR[5].x), "+v"(CUR[5].y), "+v"(CUR[5].z), "+v"(CUR[5].w), \
                   "+v"(CUR[6].x), "+v"(CUR[6].y), "+v"(CUR[6].z), "+v"(CUR[6].w), \
                   "+v"(CUR[7].x), "+v"(CUR[7].y), "+v"(CUR[7].z), "+v"(CUR[7].w));

    LOADS(b0, 0 - t)       // chunk for step 0
    LOADS(b1, 1 - t)       // chunk for step 1

    float left[8], top[4], bot[4];
#pragma unroll
    for (int r = 0; r < 8; ++r) left[r] = NEGB;
#pragma unroll
    for (int k = 0; k < 4; ++k) { top[k] = NEGB; bot[k] = NEGB; }
    float tl = (t == 0) ? 0.0f : NEGB;

#define DTW_STEP(S, CUR, FUT)                                                   \
    {                                                                           \
        WAITCUR(CUR)                                                            \
        LOADS(FUT, (S) + 2 - t)                                                 \
        const int c = (S) - t;                                                  \
        if (c >= 0 && c < 128) {                                                \
            float Rt[8][4];                                                     \
            _Pragma("unroll")                                                   \
            for (int dd = 0; dd <= 10; ++dd) {                                  \
                _Pragma("unroll")                                               \
                for (int r = 0; r < 8; ++r) {                                   \
                    const int cl = dd - r;                                      \
                    if (cl < 0 || cl > 3) continue;                             \
                    float dg, up, lf;                                           \
                    if (r == 0) { dg = (cl == 0) ? tl : top[cl - 1]; up = top[cl]; } \
                    else        { dg = (cl == 0) ? left[r - 1] : Rt[r - 1][cl - 1]; up = Rt[r - 1][cl]; } \
                    lf = (cl == 0) ? left[r] : Rt[r][cl - 1];                   \
                    float Dv = (cl == 0) ? CUR[r].x : (cl == 1) ? CUR[r].y      \
                             : (cl == 2) ? CUR[r].z : CUR[r].w;                 \
                    float mx = fmaxf(fmaxf(dg, up), lf);                        \
                    float mn = fminf(fminf(dg, up), lf);                        \
                    float md = __builtin_amdgcn_fmed3f(dg, up, lf);             \
                    float e1 = __builtin_amdgcn_exp2f(md - mx);                 \
                    float e2 = __builtin_amdgcn_exp2f(mn - mx);                 \
                    float lg = __builtin_amdgcn_logf(1.0f + e1 + e2);           \
                    Rt[r][cl] = mx + lg + Dv;                                   \
                }                                                               \
            }                                                                   \
            _Pragma("unroll")                                                   \
            for (int r = 0; r < 8; ++r) left[r] = Rt[r][3];                     \
            _Pragma("unroll")                                                   \
            for (int k = 0; k < 4; ++k) bot[k] = Rt[7][k];                      \
        }                                                                       \
        float ntl = top[3];                                                     \
        _Pragma("unroll")                                                       \
        for (int k = 0; k < 4; ++k) {                                           \
            float v = __shfl_up(bot[k], 1, 64);                                 \
            top[k] = (t == 0) ? NEGB : v;                                       \
        }                                                                       \
        tl = (t == 0) ? NEGB : ntl;                                             \
    }

    // step s: CUR = buf[s%3], FUT = buf[(s+2)%3]
    for (int p = 0; p < 63; ++p) {
        const int s = 3 * p;
        DTW_STEP(s,     b0, b2)
        DTW_STEP(s + 1, b1, b0)
        DTW_STEP(s + 2, b2, b1)
    }
    DTW_STEP(189, b0, b2)
    DTW_STEP(190, b1, b0)
#undef DTW_STEP
#undef LOADS
#undef WAITCUR

    if (t == 63) atomicAdd(out, bot[3] * (-GLN2 / 64.0f));
}

extern "C" void kernel_launch(void* const* d_in, const int* in_sizes, int n_in,
                              void* d_out, int out_size, void* d_ws, size_t ws_size,
                              hipStream_t stream) {
    const float* x = (const float*)d_in[0];   // (64, 512, 64) fp32
    const float* y = (const float*)d_in[1];   // (64, 512, 64) fp32

    float* P = (float*)d_ws;                  // 64 MB, block-linear t-domain D

    hipMemsetAsync(d_out, 0, sizeof(float), stream);
    compute_d_kernel<<<dim3(NN / 128, MM / 128, BATCH), 256, 0, stream>>>(x, y, P);
    softdtw_kernel<<<BATCH, 64, 0, stream>>>(P, (float*)d_out);
}